// Round 8
// baseline (8666.466 us; speedup 1.0000x reference)
//
#include <hip/hip_runtime.h>
#include <hip/hip_bf16.h>
#include <cstdint>

#define B_ 64
#define T_ 1024
#define I_ 128
#define R_ 2048
#define O_ 256
#define NBLK 256
#define CH 64                  // steps per chunk kernel
#define NSLOT 65               // ring slots; 64 == -1 mod 65 chains launches
#define SLOT_ELEMS (B_ * R_)   // 131072 u16 = 262144 B
#define SENTQ 0x7FC07FC07FC07FC0ull

typedef __attribute__((ext_vector_type(8))) __bf16 bf16x8;
typedef __attribute__((ext_vector_type(4))) float f32x4;
typedef __attribute__((ext_vector_type(4))) unsigned int u32x4;
typedef unsigned short u16;
typedef unsigned int u32;
typedef unsigned long long u64;

#define AT_ST(p, v) __hip_atomic_store((p), (v), __ATOMIC_RELAXED, __HIP_MEMORY_SCOPE_AGENT)

__device__ __forceinline__ u16 f2bf(float f) {
    u32 u = __builtin_bit_cast(u32, f);
    u32 r = (u + 0x7FFFu + ((u >> 16) & 1u)) >> 16;
    return (u16)r;
}

__device__ __forceinline__ bf16x8 cvt8(const float* s) {
    union { u16 h[8]; bf16x8 v; } u;
    f32x4 a = *reinterpret_cast<const f32x4*>(s);
    f32x4 b = *reinterpret_cast<const f32x4*>(s + 4);
    u.h[0] = f2bf(a[0]); u.h[1] = f2bf(a[1]); u.h[2] = f2bf(a[2]); u.h[3] = f2bf(a[3]);
    u.h[4] = f2bf(b[0]); u.h[5] = f2bf(b[1]); u.h[6] = f2bf(b[2]); u.h[7] = f2bf(b[3]);
    return u.v;
}

__device__ __forceinline__ bf16x8 ldbf8(const u16* p) {
    return *reinterpret_cast<const bf16x8*>(p);
}

// any u16 of the 16B chunk == 0x7FC0 (sentinel NaN)?  tanh output can't be.
__device__ __forceinline__ u32 sentchk(bf16x8 v) {
    u32x4 u = __builtin_bit_cast(u32x4, v);
    u32 b = 0;
    #pragma unroll
    for (int k = 0; k < 4; ++k) {
        b |= (u32)((u[k] >> 16) == 0x7FC0u);
        b |= (u32)((u[k] & 0xFFFFu) == 0x7FC0u);
    }
    return b;
}

// ---- prep kernels -------------------------------------------------------

__global__ void conv_bf16_kernel(const float* __restrict__ src,
                                 u16* __restrict__ dst, int n) {
    int stride = gridDim.x * blockDim.x;
    for (int i = blockIdx.x * blockDim.x + threadIdx.x; i < n; i += stride)
        dst[i] = f2bf(src[i]);
}

__global__ void bias_sum_kernel(const float* __restrict__ a,
                                const float* __restrict__ b,
                                float* __restrict__ c, int n) {
    int i = blockIdx.x * blockDim.x + threadIdx.x;
    if (i < n) c[i] = a[i] + b[i];
}

__global__ void fill_sent_kernel(u32* __restrict__ dst, int n) {
    int stride = gridDim.x * blockDim.x;
    for (int i = blockIdx.x * blockDim.x + threadIdx.x; i < n; i += stride)
        dst[i] = 0x7FC07FC0u;
}

// ---- chunk kernel (64 steps) --------------------------------------------
// 256 blocks x 512 threads, 1 block/CU. Block (rg=bid>>6, ns=bid&63) owns
// rows rg*16..+16 x cols ns*32..+32. NO flags, NO fences, NO vmcnt acks:
// producers sc1-write-through their h piece; consumers sc1-poll the DATA
// (sentinel bf16 NaN 0x7FC0 marks not-yet-written; tanh output can't be
// NaN). Each step writes a fresh ring slot (no address reuse in-launch ->
// no cache staleness on the sc1 path). Slot recycling for the NEXT launch:
// at step tl (post-barriers, provably after every block consumed slot
// s-1), wave 1 re-poisons its 1KB share of slot s-1.
__global__ __launch_bounds__(512, 1) void esn_chunk(
    const u16* __restrict__ Wrb, const u16* __restrict__ Wib,
    const float* __restrict__ input, const float* __restrict__ bias,
    u16* __restrict__ ring, int t0, int base)
{
    __shared__ u16 wr_lds[32 * R_];     // 131072 B, XOR-swizzled
    __shared__ u16 wi_lds[32 * I_];     // 8192 B, XOR-swizzled
    __shared__ f32x4 red2[8][2][64];    // 16384 B
    __shared__ u16 out_lds[16 * 32];    // 1024 B

    const int tid  = threadIdx.x;
    const int lane = tid & 63;
    const int w    = tid >> 6;
    const int bid  = blockIdx.x;
    const int rg   = bid >> 6;          // row-group 0..3 (16 batch rows)
    const int ns   = bid & 63;          // col-strip 0..63 (32 cols)
    const int lcol = lane & 15;
    const int lkh  = lane >> 4;         // 0..3
    const int swz  = lcol << 4;

    // ---- stage weight strips (bf16 global -> swizzled LDS), once/launch ----
    #pragma unroll
    for (int it = 0; it < 16; ++it) {
        int sl = it * 512 + tid;        // 16B slot 0..8191
        int c  = sl >> 8;               // col 0..31
        int kb = (sl & 255) * 16;       // byte offset in 4096B row
        bf16x8 v = ldbf8(Wrb + (size_t)(ns * 32 + c) * R_ + kb / 2);
        *reinterpret_cast<bf16x8*>((char*)wr_lds + c * 4096 + (kb ^ ((c & 15) << 4))) = v;
    }
    {
        int c  = tid >> 4;              // col 0..31
        int kb = (tid & 15) * 16;       // byte offset in 256B row
        bf16x8 v = ldbf8(Wib + (size_t)(ns * 32 + c) * I_ + kb / 2);
        *reinterpret_cast<bf16x8*>((char*)wi_lds + c * 256 + (kb ^ ((c & 15) << 4))) = v;
    }
    const float bs0 = bias[ns * 32 + lcol];
    const float bs1 = bias[ns * 32 + 16 + lcol];
    __syncthreads();

    int s = base;

    for (int tl = 0; tl < CH; ++tl) {
        const int t  = t0 + tl;
        const int s1 = (s + 1 == NSLOT) ? 0 : s + 1;
        const int qs = (s == 0) ? NSLOT - 1 : s - 1;
        const u16* hin  = ring + (size_t)s  * SLOT_ELEMS;
        u16*       hout = ring + (size_t)s1 * SLOT_ELEMS;

        // ---- input slice prefetch (plain cached; input is constant) ----
        f32x4 xa, xb;
        if (w < 4) {
            const float* Ax = input + ((size_t)(rg * 16 + lcol) * T_ + t) * I_ + w * 32 + lkh * 8;
            xa = *reinterpret_cast<const f32x4*>(Ax);
            xb = *reinterpret_cast<const f32x4*>(Ax + 4);
        }

        // ---- h poll+load: sc1 (IC-direct) until no sentinel remains ----
        bf16x8 h0, h1, h2, h3, h4, h5, h6, h7;
        {
            const u16* Ah = hin + (size_t)(rg * 16 + lcol) * R_ + w * 256 + lkh * 8;
            u32 bad;
            do {
                asm volatile(
                    "global_load_dwordx4 %0, %8, off sc1\n\t"
                    "global_load_dwordx4 %1, %8, off offset:64 sc1\n\t"
                    "global_load_dwordx4 %2, %8, off offset:128 sc1\n\t"
                    "global_load_dwordx4 %3, %8, off offset:192 sc1\n\t"
                    "global_load_dwordx4 %4, %8, off offset:256 sc1\n\t"
                    "global_load_dwordx4 %5, %8, off offset:320 sc1\n\t"
                    "global_load_dwordx4 %6, %8, off offset:384 sc1\n\t"
                    "global_load_dwordx4 %7, %8, off offset:448 sc1\n\t"
                    "s_waitcnt vmcnt(0)"
                    : "=&v"(h0), "=&v"(h1), "=&v"(h2), "=&v"(h3),
                      "=&v"(h4), "=&v"(h5), "=&v"(h6), "=&v"(h7)
                    : "v"(Ah)
                    : "memory");
                __builtin_amdgcn_sched_barrier(0);
                bad = sentchk(h0) | sentchk(h1) | sentchk(h2) | sentchk(h3) |
                      sentchk(h4) | sentchk(h5) | sentchk(h6) | sentchk(h7);
            } while (__any((int)bad));
        }

        f32x4 acc0 = {0.f, 0.f, 0.f, 0.f};
        f32x4 acc1 = {0.f, 0.f, 0.f, 0.f};

        // ---- input projection (waves 0..3 cover K_in=128) ----
        if (w < 4) {
            union { u16 hh[8]; bf16x8 v; } ua;
            f32x4 a0 = xa, a1 = xb;
            ua.hh[0] = f2bf(a0[0]); ua.hh[1] = f2bf(a0[1]);
            ua.hh[2] = f2bf(a0[2]); ua.hh[3] = f2bf(a0[3]);
            ua.hh[4] = f2bf(a1[0]); ua.hh[5] = f2bf(a1[1]);
            ua.hh[6] = f2bf(a1[2]); ua.hh[7] = f2bf(a1[3]);
            int kb2 = (w * 32 + lkh * 8) * 2;
            bf16x8 b0 = *reinterpret_cast<const bf16x8*>(
                (const char*)wi_lds + lcol * 256 + (kb2 ^ swz));
            bf16x8 b1 = *reinterpret_cast<const bf16x8*>(
                (const char*)wi_lds + (16 + lcol) * 256 + (kb2 ^ swz));
            acc0 = __builtin_amdgcn_mfma_f32_16x16x32_bf16(ua.v, b0, acc0, 0, 0, 0);
            acc1 = __builtin_amdgcn_mfma_f32_16x16x32_bf16(ua.v, b1, acc1, 0, 0, 0);
        }

        // ---- recurrent: this wave's K-eighth from LDS B-frags ----
        {
            #define RSTEP(J, HJ)                                                   \
            {                                                                      \
                int kb2 = (w * 256 + (J) * 32 + lkh * 8) * 2;                      \
                bf16x8 b0 = *reinterpret_cast<const bf16x8*>(                      \
                    (const char*)wr_lds + lcol * 4096 + (kb2 ^ swz));              \
                bf16x8 b1 = *reinterpret_cast<const bf16x8*>(                      \
                    (const char*)wr_lds + (16 + lcol) * 4096 + (kb2 ^ swz));       \
                acc0 = __builtin_amdgcn_mfma_f32_16x16x32_bf16(HJ, b0, acc0, 0, 0, 0); \
                acc1 = __builtin_amdgcn_mfma_f32_16x16x32_bf16(HJ, b1, acc1, 0, 0, 0); \
            }
            RSTEP(0, h0) RSTEP(1, h1) RSTEP(2, h2) RSTEP(3, h3)
            RSTEP(4, h4) RSTEP(5, h5) RSTEP(6, h6) RSTEP(7, h7)
            #undef RSTEP
        }

        __syncthreads();                 // #1: prev-step tail/poison done
        red2[w][0][lane] = acc0;
        red2[w][1][lane] = acc1;
        __syncthreads();                 // #2: partials visible

        // ---- wave 0: reduce, tanh, store piece (sc1 WT, no ack needed) ----
        if (w == 0) {
            #pragma unroll
            for (int nh = 0; nh < 2; ++nh) {
                f32x4 sv = red2[0][nh][lane];
                #pragma unroll
                for (int ww = 1; ww < 8; ++ww) sv += red2[ww][nh][lane];
                const float bsv = nh ? bs1 : bs0;
                #pragma unroll
                for (int i2 = 0; i2 < 4; ++i2) {
                    float v = tanhf(sv[i2] + bsv);
                    // C/D layout: col = lane&15, row = (lane>>4)*4 + reg
                    out_lds[(lkh * 4 + i2) * 32 + nh * 16 + lcol] = f2bf(v);
                }
            }
            union { bf16x8 v; u64 qq[2]; } ov;
            ov.v = ldbf8(&out_lds[lane * 8]);
            u16* dst = hout + (size_t)(rg * 16 + (lane >> 2)) * R_ + ns * 32 + (lane & 3) * 8;
            AT_ST(reinterpret_cast<u64*>(dst), ov.qq[0]);
            AT_ST(reinterpret_cast<u64*>(dst) + 1, ov.qq[1]);
        }

        // ---- wave 1: re-poison own 1KB share of the slot consumed at tl-1.
        // Safe: our poll of slot s passing proves every producer stored s,
        // which it did only after fully consuming slot s-1. ----
        if (w == 1) {
            u16* pz = ring + (size_t)qs * SLOT_ELEMS
                      + (size_t)(rg * 16 + (lane >> 2)) * R_ + ns * 32 + (lane & 3) * 8;
            AT_ST(reinterpret_cast<u64*>(pz), SENTQ);
            AT_ST(reinterpret_cast<u64*>(pz) + 1, SENTQ);
        }

        s = s1;
    }
}

// ---- readout ------------------------------------------------------------
__global__ __launch_bounds__(128) void readout_kernel(
    const u16* __restrict__ h, const u16* __restrict__ Wo,
    const float* __restrict__ b_out, float* __restrict__ out)
{
    const int lane = threadIdx.x & 63;
    const int wid  = threadIdx.x >> 6;
    const int g    = blockIdx.x * 2 + wid;   // 0..63
    const int m    = g >> 4;
    const int n    = g & 15;
    const int koff = (lane >> 4) * 8;
    const int b    = m * 16 + (lane & 15);
    const int col  = n * 16 + (lane & 15);

    f32x4 acc0 = {0.f,0.f,0.f,0.f};
    f32x4 acc1 = {0.f,0.f,0.f,0.f};
    f32x4 acc2 = {0.f,0.f,0.f,0.f};
    f32x4 acc3 = {0.f,0.f,0.f,0.f};

    const u16* Ah = h + (size_t)b * R_ + koff;
    const u16* Bh = Wo + (size_t)col * R_ + koff;
    #pragma unroll 4
    for (int kc = 0; kc < 64; kc += 4) {
        acc0 = __builtin_amdgcn_mfma_f32_16x16x32_bf16(ldbf8(Ah + (kc + 0) * 32), ldbf8(Bh + (kc + 0) * 32), acc0, 0, 0, 0);
        acc1 = __builtin_amdgcn_mfma_f32_16x16x32_bf16(ldbf8(Ah + (kc + 1) * 32), ldbf8(Bh + (kc + 1) * 32), acc1, 0, 0, 0);
        acc2 = __builtin_amdgcn_mfma_f32_16x16x32_bf16(ldbf8(Ah + (kc + 2) * 32), ldbf8(Bh + (kc + 2) * 32), acc2, 0, 0, 0);
        acc3 = __builtin_amdgcn_mfma_f32_16x16x32_bf16(ldbf8(Ah + (kc + 3) * 32), ldbf8(Bh + (kc + 3) * 32), acc3, 0, 0, 0);
    }

    f32x4 sv = acc0 + acc1 + acc2 + acc3;
    const float bo = b_out[col];
    #pragma unroll
    for (int i2 = 0; i2 < 4; ++i2) {
        int row = m * 16 + (lane >> 4) * 4 + i2;
        out[(size_t)row * O_ + col] = sv[i2] + bo;
    }
}

// ---- launch -------------------------------------------------------------

extern "C" void kernel_launch(void* const* d_in, const int* in_sizes, int n_in,
                              void* d_out, int out_size, void* d_ws, size_t ws_size,
                              hipStream_t stream) {
    const float* in    = (const float*)d_in[0];
    const float* Winw  = (const float*)d_in[1];
    const float* Winb  = (const float*)d_in[2];
    const float* Wresw = (const float*)d_in[3];
    const float* Wresb = (const float*)d_in[4];
    const float* Woutw = (const float*)d_in[5];
    const float* Woutb = (const float*)d_in[6];
    float* out = (float*)d_out;

    char* ws = (char*)d_ws;
    u16*   Wrb  = (u16*)(ws);                      // 2048*2048*2 = 8388608
    u16*   Wib  = (u16*)(ws + 8388608);            // 2048*128*2  = 524288
    u16*   Wob  = (u16*)(ws + 8912896);            // 256*2048*2  = 1048576
    float* bias = (float*)(ws + 9961472);          // 2048*4      = 8192
    u16*   ring = (u16*)(ws + 9969664);            // 65*262144   = 17039360
    // total: 27009024 bytes (~25.8 MB)

    conv_bf16_kernel<<<2048, 256, 0, stream>>>(Wresw, Wrb, R_ * R_);
    conv_bf16_kernel<<<256, 256, 0, stream>>>(Winw, Wib, R_ * I_);
    conv_bf16_kernel<<<512, 256, 0, stream>>>(Woutw, Wob, O_ * R_);
    bias_sum_kernel<<<8, 256, 0, stream>>>(Winb, Wresb, bias, R_);
    // slots 1..64 = sentinel, slot 0 = h0 = zeros (re-done every launch ->
    // re-entrant despite in-kernel poisoning)
    fill_sent_kernel<<<4096, 256, 0, stream>>>(
        (u32*)(ring + SLOT_ELEMS), (NSLOT - 1) * SLOT_ELEMS / 2);
    hipMemsetAsync(ring, 0, SLOT_ELEMS * sizeof(u16), stream);

    int s = 0;
    for (int c = 0; c < T_ / CH; ++c) {
        esn_chunk<<<NBLK, 512, 0, stream>>>(Wrb, Wib, in, bias, ring, c * CH, s);
        s = (s + CH) % NSLOT;
    }
    // s now indexes the slot holding h(T)
    readout_kernel<<<32, 128, 0, stream>>>(ring + (size_t)s * SLOT_ELEMS,
                                           Wob, Woutb, out);
}

// Round 11
// 5095.412 us; speedup vs baseline: 1.7008x; 1.7008x over previous
//
#include <hip/hip_runtime.h>
#include <hip/hip_bf16.h>
#include <cstdint>

#define B_ 64
#define T_ 1024
#define I_ 128
#define R_ 2048
#define O_ 256
#define NBLK 256
#define NSLOT 65
#define SLOTB 32768                    // 8 rows x 2048 bf16 x 2B
#define RSTRIDE (NSLOT * SLOTB)        // per-group ring bytes = 2129920

typedef __attribute__((ext_vector_type(8))) __bf16 bf16x8;
typedef __attribute__((ext_vector_type(4))) float f32x4;
typedef __attribute__((ext_vector_type(4))) unsigned int u32x4;
typedef unsigned short u16;
typedef unsigned int u32;
typedef unsigned long long u64;

#define AT_LDR(p) __hip_atomic_load((p), __ATOMIC_RELAXED, __HIP_MEMORY_SCOPE_AGENT)

__device__ __forceinline__ u16 f2bf(float f) {
    u32 u = __builtin_bit_cast(u32, f);
    u32 r = (u + 0x7FFFu + ((u >> 16) & 1u)) >> 16;
    return (u16)r;
}

__device__ __forceinline__ bf16x8 cvt8r(f32x4 a, f32x4 b) {
    union { u16 h[8]; bf16x8 v; } u;
    u.h[0] = f2bf(a[0]); u.h[1] = f2bf(a[1]); u.h[2] = f2bf(a[2]); u.h[3] = f2bf(a[3]);
    u.h[4] = f2bf(b[0]); u.h[5] = f2bf(b[1]); u.h[6] = f2bf(b[2]); u.h[7] = f2bf(b[3]);
    return u.v;
}

__device__ __forceinline__ bf16x8 ldbf8(const u16* p) {
    return *reinterpret_cast<const bf16x8*>(p);
}

// any u16 == 0x7FC0 (bf16 NaN sentinel; tanh output can't be NaN)
__device__ __forceinline__ u32 sentchk(bf16x8 v) {
    u32x4 u = __builtin_bit_cast(u32x4, v);
    u32 b = 0;
    #pragma unroll
    for (int k = 0; k < 4; ++k) {
        b |= (u32)((u[k] >> 16) == 0x7FC0u);
        b |= (u32)((u[k] & 0xFFFFu) == 0x7FC0u);
    }
    return b;
}

// ---- prep kernels -------------------------------------------------------

__global__ void conv_bf16_kernel(const float* __restrict__ src,
                                 u16* __restrict__ dst, int n) {
    int stride = gridDim.x * blockDim.x;
    for (int i = blockIdx.x * blockDim.x + threadIdx.x; i < n; i += stride)
        dst[i] = f2bf(src[i]);
}

__global__ void bias_sum_kernel(const float* __restrict__ a,
                                const float* __restrict__ b,
                                float* __restrict__ c, int n) {
    int i = blockIdx.x * blockDim.x + threadIdx.x;
    if (i < n) c[i] = a[i] + b[i];
}

// ring: 8 groups x 65 slots x 32768B. slot 0 zero (h0), slots 1..64 NaN sentinel
__global__ void ring_init_kernel(u32* __restrict__ ring) {
    const int perg = NSLOT * (SLOTB / 4);     // 532480 u32
    const int total = 8 * perg;
    int stride = gridDim.x * blockDim.x;
    for (int idx = blockIdx.x * blockDim.x + threadIdx.x; idx < total; idx += stride) {
        int within = idx % perg;
        int slot = within / (SLOTB / 4);
        ring[idx] = slot ? 0x7FC07FC0u : 0u;
    }
}

// ---- persistent XCD-local recurrent kernel (bf16) -----------------------
// 256 blocks x 512 threads, 1 block/CU (LDS-forced, 82KB). Election (r10,
// hardened): mode A = group g owns batch rows g*8..+8 on its own XCD; mode
// B fallback = roles from global counter, all polls sc1 (IC). Block (g,ns)
// owns cols ns*64..+64. Wave w owns K-eighth [w*256,+256) x all 4 col-
// tiles; its W_res fragments live in 128 VGPRs (32x asm-volatile-loaded
// bf16x8 -> no remat). h ring slot = 8 rows x 4KB, bf16, NaN-sentinel
// data-poll; A-rows 8-15 read a shared zero page. Stores sc1 write-through;
// polls sc0 (L2) with sticky escape to sc1 after 64 spins.
__global__ __launch_bounds__(512, 1) void esn_persist(
    const u16* __restrict__ Wrb, const u16* __restrict__ Wib,
    const float* __restrict__ input, const float* __restrict__ bias,
    u16* __restrict__ ring, const u16* __restrict__ zpage,
    u32* __restrict__ cnt, u16* __restrict__ hfinal)
{
    __shared__ f32x4 red[8][4][64];     // 32768 B
    __shared__ u16 xout[8][64];         // 1024 B
    __shared__ char pad_lds[49152];     // force 1 block/CU (total ~82KB)
    __shared__ int s_grp, s_ns, s_mode;

    const int tid  = threadIdx.x;
    const int lane = tid & 63;
    const int w    = tid >> 6;
    const int lcol = lane & 15;         // B col within tile / A row
    const int lkh  = lane >> 4;         // 0..3
    const int arow = lcol;              // A row 0..15 (8..15 = zero page)

    // keep pad_lds alive without ever touching it (cnt[15] is always 0)
    if (cnt[15] == 0xDEADBEEFu) {
        pad_lds[tid] = 1;
        __syncthreads();
        hfinal[0] = (u16)pad_lds[0];
    }

    // ---- hardened two-counter election ----
    if (tid == 0) {
        u32 xcd;
        asm volatile("s_getreg_b32 %0, hwreg(20, 0, 32)" : "=s"(xcd));
        xcd &= 7;
        int slotA = (int)__hip_atomic_fetch_add(&cnt[xcd], 1u, __ATOMIC_RELAXED,
                                                __HIP_MEMORY_SCOPE_AGENT);
        int gslot = (int)__hip_atomic_fetch_add(&cnt[8], 1u, __ATOMIC_ACQ_REL,
                                                __HIP_MEMORY_SCOPE_AGENT);
        while (AT_LDR(&cnt[8]) < 256u) { }
        u32 c[8], tot;
        do {                              // re-read until all adds visible
            tot = 0;
            #pragma unroll
            for (int i = 0; i < 8; ++i) { c[i] = AT_LDR(&cnt[i]); tot += c[i]; }
        } while (tot != 256u);
        int bal = 1;
        #pragma unroll
        for (int i = 0; i < 8; ++i) bal &= (c[i] == 32u);
        s_mode = bal;
        s_grp  = bal ? (int)xcd : (gslot >> 5);
        s_ns   = bal ? (slotA & 31) : (gslot & 31);
    }
    __syncthreads();
    const int grp = s_grp;
    const int ns  = s_ns;
    bool ic = (s_mode == 0);              // mode B: IC path always

    // ---- stage W_res fragments into REGISTERS (asm volatile: no remat) ----
    bf16x8 wf0[8], wf1[8], wf2[8], wf3[8];
    {
        const u16* bp0 = Wrb + (size_t)(ns * 64 +  0 + lcol) * R_ + w * 256 + lkh * 8;
        const u16* bp1 = Wrb + (size_t)(ns * 64 + 16 + lcol) * R_ + w * 256 + lkh * 8;
        const u16* bp2 = Wrb + (size_t)(ns * 64 + 32 + lcol) * R_ + w * 256 + lkh * 8;
        const u16* bp3 = Wrb + (size_t)(ns * 64 + 48 + lcol) * R_ + w * 256 + lkh * 8;
        #define WL(dst, bp, OFF) \
            asm volatile("global_load_dwordx4 %0, %1, off offset:" OFF \
                         : "=v"(dst) : "v"(bp))
        WL(wf0[0], bp0, "0");   WL(wf0[1], bp0, "64");  WL(wf0[2], bp0, "128");
        WL(wf0[3], bp0, "192"); WL(wf0[4], bp0, "256"); WL(wf0[5], bp0, "320");
        WL(wf0[6], bp0, "384"); WL(wf0[7], bp0, "448");
        WL(wf1[0], bp1, "0");   WL(wf1[1], bp1, "64");  WL(wf1[2], bp1, "128");
        WL(wf1[3], bp1, "192"); WL(wf1[4], bp1, "256"); WL(wf1[5], bp1, "320");
        WL(wf1[6], bp1, "384"); WL(wf1[7], bp1, "448");
        WL(wf2[0], bp2, "0");   WL(wf2[1], bp2, "64");  WL(wf2[2], bp2, "128");
        WL(wf2[3], bp2, "192"); WL(wf2[4], bp2, "256"); WL(wf2[5], bp2, "320");
        WL(wf2[6], bp2, "384"); WL(wf2[7], bp2, "448");
        WL(wf3[0], bp3, "0");   WL(wf3[1], bp3, "64");  WL(wf3[2], bp3, "128");
        WL(wf3[3], bp3, "192"); WL(wf3[4], bp3, "256"); WL(wf3[5], bp3, "320");
        WL(wf3[6], bp3, "384"); WL(wf3[7], bp3, "448");
        #undef WL
    }
    // input-projection W fragments (waves 0-3, tile w)
    bf16x8 wi[4];
    float bs = 0.f;
    if (w < 4) {
        const u16* wp = Wib + (size_t)(ns * 64 + w * 16 + lcol) * I_ + lkh * 8;
        asm volatile("global_load_dwordx4 %0, %1, off"            : "=v"(wi[0]) : "v"(wp));
        asm volatile("global_load_dwordx4 %0, %1, off offset:64"  : "=v"(wi[1]) : "v"(wp));
        asm volatile("global_load_dwordx4 %0, %1, off offset:128" : "=v"(wi[2]) : "v"(wp));
        asm volatile("global_load_dwordx4 %0, %1, off offset:192" : "=v"(wi[3]) : "v"(wp));
        bs = bias[ns * 64 + w * 16 + lcol];
    }
    asm volatile("s_waitcnt vmcnt(0)" ::: "memory");
    __builtin_amdgcn_sched_barrier(0);

    char* ringB = (char*)ring + (size_t)grp * RSTRIDE;
    const char* zb = (const char*)zpage;
    const float* xrow = input + (size_t)(grp * 8 + (arow & 7)) * T_ * I_;

    #define LOAD8(F)                                                          \
        asm volatile(                                                         \
            "global_load_dwordx4 %0, %8, off " F "\n\t"                       \
            "global_load_dwordx4 %1, %8, off offset:64 " F "\n\t"             \
            "global_load_dwordx4 %2, %8, off offset:128 " F "\n\t"            \
            "global_load_dwordx4 %3, %8, off offset:192 " F "\n\t"            \
            "global_load_dwordx4 %4, %8, off offset:256 " F "\n\t"            \
            "global_load_dwordx4 %5, %8, off offset:320 " F "\n\t"            \
            "global_load_dwordx4 %6, %8, off offset:384 " F "\n\t"            \
            "global_load_dwordx4 %7, %8, off offset:448 " F "\n\t"            \
            "s_waitcnt vmcnt(0)"                                              \
            : "=&v"(h0), "=&v"(h1), "=&v"(h2), "=&v"(h3),                     \
              "=&v"(h4), "=&v"(h5), "=&v"(h6), "=&v"(h7)                      \
            : "v"(Ah)                                                         \
            : "memory")

    int rs = 0;
    for (int t = 0; t < T_; ++t) {
        const int wsl = (rs + 1 == NSLOT) ? 0 : rs + 1;
        const int ps  = (rs == 0) ? NSLOT - 1 : rs - 1;
        const char* slotR = ringB + (size_t)rs  * SLOTB;
        char*       slotW = ringB + (size_t)wsl * SLOTB;
        char*       slotP = ringB + (size_t)ps  * SLOTB;

        // ---- input projection (waves 0-3, tile w; independent of h) ----
        f32x4 facc = {0.f, 0.f, 0.f, 0.f};
        if (w < 4) {
            const float* Ax = xrow + (size_t)t * I_ + lkh * 8;
            const f32x4 z4 = {0.f, 0.f, 0.f, 0.f};
            #pragma unroll
            for (int kc = 0; kc < 4; ++kc) {
                f32x4 xa = z4, xb = z4;
                if (arow < 8) {
                    xa = *reinterpret_cast<const f32x4*>(Ax + kc * 32);
                    xb = *reinterpret_cast<const f32x4*>(Ax + kc * 32 + 4);
                }
                facc = __builtin_amdgcn_mfma_f32_16x16x32_bf16(cvt8r(xa, xb), wi[kc], facc, 0, 0, 0);
            }
        }

        // ---- poll+load h A-fragments (NaN sentinel; rows 8-15 = zero page) ----
        const char* base = (arow < 8) ? (slotR + arow * 4096) : zb;
        const char* Ah = base + (size_t)(w * 256 + lkh * 8) * 2;
        bf16x8 h0, h1, h2, h3, h4, h5, h6, h7;
        {
            u32 bad; int anybad; int spins = 0;
            do {
                if (ic) { LOAD8("sc1"); } else { LOAD8("sc0"); }
                __builtin_amdgcn_sched_barrier(0);
                bad = sentchk(h0) | sentchk(h1) | sentchk(h2) | sentchk(h3) |
                      sentchk(h4) | sentchk(h5) | sentchk(h6) | sentchk(h7);
                anybad = __any((int)bad);
                if (anybad && !ic && ++spins >= 64) ic = true;   // sticky escape
            } while (anybad);
        }

        // ---- recurrent MFMAs: K-eighth w, 4 col-tiles, weights in regs ----
        f32x4 acc0 = {0.f,0.f,0.f,0.f}, acc1 = {0.f,0.f,0.f,0.f};
        f32x4 acc2 = {0.f,0.f,0.f,0.f}, acc3 = {0.f,0.f,0.f,0.f};
        #define RSTEP(J, HJ)                                                      \
            acc0 = __builtin_amdgcn_mfma_f32_16x16x32_bf16(HJ, wf0[J], acc0, 0, 0, 0); \
            acc1 = __builtin_amdgcn_mfma_f32_16x16x32_bf16(HJ, wf1[J], acc1, 0, 0, 0); \
            acc2 = __builtin_amdgcn_mfma_f32_16x16x32_bf16(HJ, wf2[J], acc2, 0, 0, 0); \
            acc3 = __builtin_amdgcn_mfma_f32_16x16x32_bf16(HJ, wf3[J], acc3, 0, 0, 0);
        RSTEP(0, h0) RSTEP(1, h1) RSTEP(2, h2) RSTEP(3, h3)
        RSTEP(4, h4) RSTEP(5, h5) RSTEP(6, h6) RSTEP(7, h7)
        #undef RSTEP

        red[w][0][lane] = acc0;
        red[w][1][lane] = acc1;
        red[w][2][lane] = acc2;
        red[w][3][lane] = acc3;
        __syncthreads();                 // b1: all partials visible

        // ---- tail: wave w<4 reduces tile w, adds xin+bias, tanh ----
        if (w < 4) {
            f32x4 tot = red[0][w][lane];
            #pragma unroll
            for (int ww = 1; ww < 8; ++ww) tot += red[ww][w][lane];
            tot += facc;
            #pragma unroll
            for (int i = 0; i < 4; ++i) {
                int orow = lkh * 4 + i;  // C layout: col=lane&15, row=lkh*4+i
                if (orow < 8)
                    xout[orow][w * 16 + lcol] = f2bf(tanhf(tot[i] + bs));
            }
        }
        __syncthreads();                 // b2: xout complete

        if (w == 0) {                    // publish: sc1 write-through
            bf16x8 v = ldbf8(&xout[lane >> 3][(lane & 7) * 8]);
            char* dst = slotW + (size_t)(lane >> 3) * 4096 + ns * 128 + (lane & 7) * 16;
            asm volatile("global_store_dwordx4 %0, %1, off sc1"
                         :: "v"(dst), "v"(v) : "memory");
        }
        if (w == 1) {                    // re-poison slot consumed at t-1
            u32x4 sq = {0x7FC07FC0u, 0x7FC07FC0u, 0x7FC07FC0u, 0x7FC07FC0u};
            char* dst = slotP + (size_t)(lane >> 3) * 4096 + ns * 128 + (lane & 7) * 16;
            asm volatile("global_store_dwordx4 %0, %1, off sc1"
                         :: "v"(dst), "v"(sq) : "memory");
        }
        if (w == 2 && t == T_ - 1) {     // final h -> hfinal (plain stores)
            bf16x8 v = ldbf8(&xout[lane >> 3][(lane & 7) * 8]);
            *reinterpret_cast<bf16x8*>(
                hfinal + (size_t)(grp * 8 + (lane >> 3)) * R_ + ns * 64 + (lane & 7) * 8) = v;
        }
        rs = wsl;
    }
    #undef LOAD8
}

// ---- readout ------------------------------------------------------------
__global__ __launch_bounds__(128) void readout_kernel(
    const u16* __restrict__ h, const u16* __restrict__ Wo,
    const float* __restrict__ b_out, float* __restrict__ out)
{
    const int lane = threadIdx.x & 63;
    const int wid  = threadIdx.x >> 6;
    const int g    = blockIdx.x * 2 + wid;   // 0..63
    const int m    = g >> 4;
    const int n    = g & 15;
    const int koff = (lane >> 4) * 8;
    const int b    = m * 16 + (lane & 15);
    const int col  = n * 16 + (lane & 15);

    f32x4 acc0 = {0.f,0.f,0.f,0.f};
    f32x4 acc1 = {0.f,0.f,0.f,0.f};
    f32x4 acc2 = {0.f,0.f,0.f,0.f};
    f32x4 acc3 = {0.f,0.f,0.f,0.f};

    const u16* Ah = h + (size_t)b * R_ + koff;
    const u16* Bh = Wo + (size_t)col * R_ + koff;
    #pragma unroll 4
    for (int kc = 0; kc < 64; kc += 4) {
        acc0 = __builtin_amdgcn_mfma_f32_16x16x32_bf16(ldbf8(Ah + (kc + 0) * 32), ldbf8(Bh + (kc + 0) * 32), acc0, 0, 0, 0);
        acc1 = __builtin_amdgcn_mfma_f32_16x16x32_bf16(ldbf8(Ah + (kc + 1) * 32), ldbf8(Bh + (kc + 1) * 32), acc1, 0, 0, 0);
        acc2 = __builtin_amdgcn_mfma_f32_16x16x32_bf16(ldbf8(Ah + (kc + 2) * 32), ldbf8(Bh + (kc + 2) * 32), acc2, 0, 0, 0);
        acc3 = __builtin_amdgcn_mfma_f32_16x16x32_bf16(ldbf8(Ah + (kc + 3) * 32), ldbf8(Bh + (kc + 3) * 32), acc3, 0, 0, 0);
    }

    f32x4 s = acc0 + acc1 + acc2 + acc3;
    const float bo = b_out[col];
    #pragma unroll
    for (int i2 = 0; i2 < 4; ++i2) {
        int row = m * 16 + (lane >> 4) * 4 + i2;
        out[(size_t)row * O_ + col] = s[i2] + bo;
    }
}

// ---- launch -------------------------------------------------------------

extern "C" void kernel_launch(void* const* d_in, const int* in_sizes, int n_in,
                              void* d_out, int out_size, void* d_ws, size_t ws_size,
                              hipStream_t stream) {
    const float* in    = (const float*)d_in[0];
    const float* Winw  = (const float*)d_in[1];
    const float* Winb  = (const float*)d_in[2];
    const float* Wresw = (const float*)d_in[3];
    const float* Wresb = (const float*)d_in[4];
    const float* Woutw = (const float*)d_in[5];
    const float* Woutb = (const float*)d_in[6];
    float* out = (float*)d_out;

    char* ws = (char*)d_ws;
    u16*   Wrb    = (u16*)(ws);                    // 2048*2048*2 = 8388608
    u16*   Wib    = (u16*)(ws + 8388608);          // 2048*128*2  = 524288
    u16*   Wob    = (u16*)(ws + 8912896);          // 256*2048*2  = 1048576
    float* bias   = (float*)(ws + 9961472);        // 2048*4      = 8192
    u16*   hfinal = (u16*)(ws + 9969664);          // 64*2048*2   = 262144
    u16*   zpage  = (u16*)(ws + 10231808);         // 4096
    u32*   cnt    = (u32*)(ws + 10235904);         // 64
    u16*   ring   = (u16*)(ws + 10235968);         // 8*65*32768  = 17039360
    // total: 27275328 bytes (~26 MB)

    conv_bf16_kernel<<<2048, 256, 0, stream>>>(Wresw, Wrb, R_ * R_);
    conv_bf16_kernel<<<256, 256, 0, stream>>>(Winw, Wib, R_ * I_);
    conv_bf16_kernel<<<512, 256, 0, stream>>>(Woutw, Wob, O_ * R_);
    bias_sum_kernel<<<8, 256, 0, stream>>>(Winb, Wresb, bias, R_);
    ring_init_kernel<<<4096, 256, 0, stream>>>((u32*)ring);
    hipMemsetAsync(zpage, 0, 4096 + 64, stream);   // zero page + counters

    esn_persist<<<NBLK, 512, 0, stream>>>(Wrb, Wib, in, bias,
                                          ring, zpage, cnt, hfinal);

    readout_kernel<<<32, 128, 0, stream>>>(hfinal, Wob, Woutb, out);
}

// Round 12
// 4898.993 us; speedup vs baseline: 1.7690x; 1.0401x over previous
//
#include <hip/hip_runtime.h>
#include <hip/hip_bf16.h>
#include <cstdint>

#define B_ 64
#define T_ 1024
#define I_ 128
#define R_ 2048
#define O_ 256
#define NBLK 256
#define NSLOT 65
#define SLOTB 32768                    // 8 rows x 2048 bf16 x 2B
#define RSTRIDE (NSLOT * SLOTB)        // per-group ring bytes = 2129920

typedef __attribute__((ext_vector_type(8))) __bf16 bf16x8;
typedef __attribute__((ext_vector_type(4))) float f32x4;
typedef __attribute__((ext_vector_type(4))) unsigned int u32x4;
typedef unsigned short u16;
typedef unsigned int u32;
typedef unsigned long long u64;

#define AT_LDR(p) __hip_atomic_load((p), __ATOMIC_RELAXED, __HIP_MEMORY_SCOPE_AGENT)

__device__ __forceinline__ u16 f2bf(float f) {
    u32 u = __builtin_bit_cast(u32, f);
    u32 r = (u + 0x7FFFu + ((u >> 16) & 1u)) >> 16;
    return (u16)r;
}

__device__ __forceinline__ bf16x8 cvt8r(f32x4 a, f32x4 b) {
    union { u16 h[8]; bf16x8 v; } u;
    u.h[0] = f2bf(a[0]); u.h[1] = f2bf(a[1]); u.h[2] = f2bf(a[2]); u.h[3] = f2bf(a[3]);
    u.h[4] = f2bf(b[0]); u.h[5] = f2bf(b[1]); u.h[6] = f2bf(b[2]); u.h[7] = f2bf(b[3]);
    return u.v;
}

__device__ __forceinline__ bf16x8 ldbf8(const u16* p) {
    return *reinterpret_cast<const bf16x8*>(p);
}

// any u16 == 0x7FC0 (bf16 NaN sentinel; tanh output can't be NaN)
__device__ __forceinline__ u32 sentchk(bf16x8 v) {
    u32x4 u = __builtin_bit_cast(u32x4, v);
    u32 b = 0;
    #pragma unroll
    for (int k = 0; k < 4; ++k) {
        b |= (u32)((u[k] >> 16) == 0x7FC0u);
        b |= (u32)((u[k] & 0xFFFFu) == 0x7FC0u);
    }
    return b;
}

// ---- prep kernels -------------------------------------------------------

__global__ void conv_bf16_kernel(const float* __restrict__ src,
                                 u16* __restrict__ dst, int n) {
    int stride = gridDim.x * blockDim.x;
    for (int i = blockIdx.x * blockDim.x + threadIdx.x; i < n; i += stride)
        dst[i] = f2bf(src[i]);
}

__global__ void bias_sum_kernel(const float* __restrict__ a,
                                const float* __restrict__ b,
                                float* __restrict__ c, int n) {
    int i = blockIdx.x * blockDim.x + threadIdx.x;
    if (i < n) c[i] = a[i] + b[i];
}

// ring: 8 groups x 65 slots x 32768B. slot 0 zero (h0), slots 1..64 NaN sentinel
__global__ void ring_init_kernel(u32* __restrict__ ring) {
    const int perg = NSLOT * (SLOTB / 4);     // 532480 u32
    const int total = 8 * perg;
    int stride = gridDim.x * blockDim.x;
    for (int idx = blockIdx.x * blockDim.x + threadIdx.x; idx < total; idx += stride) {
        int within = idx % perg;
        int slot = within / (SLOTB / 4);
        ring[idx] = slot ? 0x7FC07FC0u : 0u;
    }
}

// ---- persistent XCD-local recurrent kernel (bf16) -----------------------
// r11 structure (PASS, 5095us) with the VGPR spill fixed: per wave, W_res
// col-tile 0 lives in LDS (8KB/wave, conflict-free lane-stride-16B layout,
// ds_read_b128) and col-tiles 1-3 live in 96 VGPRs (asm-volatile loads, no
// remat). Total ~190 VGPR (no scratch), ~97KB LDS (still 1 block/CU).
// __launch_bounds__(512,2) = 8 waves/CU -> 256-VGPR cap for the allocator.
__global__ __launch_bounds__(512, 2) void esn_persist(
    const u16* __restrict__ Wrb, const u16* __restrict__ Wib,
    const float* __restrict__ input, const float* __restrict__ bias,
    u16* __restrict__ ring, const u16* __restrict__ zpage,
    u32* __restrict__ cnt, u16* __restrict__ hfinal)
{
    __shared__ char wlds[65536];        // 8 waves x 8 chunks x 64 lanes x 16B
    __shared__ f32x4 red[8][4][64];     // 32768 B
    __shared__ u16 xout[8][64];         // 1024 B
    __shared__ int s_grp, s_ns, s_mode; // total ~97 KB -> 1 block/CU

    const int tid  = threadIdx.x;
    const int lane = tid & 63;
    const int w    = tid >> 6;
    const int lcol = lane & 15;         // B col within tile / A row
    const int lkh  = lane >> 4;         // 0..3
    const int arow = lcol;              // A row 0..15 (8..15 = zero page)

    // ---- hardened two-counter election ----
    if (tid == 0) {
        u32 xcd;
        asm volatile("s_getreg_b32 %0, hwreg(20, 0, 32)" : "=s"(xcd));
        xcd &= 7;
        int slotA = (int)__hip_atomic_fetch_add(&cnt[xcd], 1u, __ATOMIC_RELAXED,
                                                __HIP_MEMORY_SCOPE_AGENT);
        int gslot = (int)__hip_atomic_fetch_add(&cnt[8], 1u, __ATOMIC_ACQ_REL,
                                                __HIP_MEMORY_SCOPE_AGENT);
        while (AT_LDR(&cnt[8]) < 256u) { }
        u32 c[8], tot;
        do {                              // re-read until all adds visible
            tot = 0;
            #pragma unroll
            for (int i = 0; i < 8; ++i) { c[i] = AT_LDR(&cnt[i]); tot += c[i]; }
        } while (tot != 256u);
        int bal = 1;
        #pragma unroll
        for (int i = 0; i < 8; ++i) bal &= (c[i] == 32u);
        s_mode = bal;
        s_grp  = bal ? (int)xcd : (gslot >> 5);
        s_ns   = bal ? (slotA & 31) : (gslot & 31);
    }
    __syncthreads();
    const int grp = s_grp;
    const int ns  = s_ns;
    bool ic = (s_mode == 0);              // mode B: IC path always

    // ---- stage W_res: col-tile 0 -> LDS (wave-local region) ----
    {
        const u16* bp0 = Wrb + (size_t)(ns * 64 + lcol) * R_ + w * 256 + lkh * 8;
        #pragma unroll
        for (int j = 0; j < 8; ++j) {
            *reinterpret_cast<bf16x8*>(wlds + ((size_t)(w * 8 + j) * 64 + lane) * 16)
                = ldbf8(bp0 + j * 32);
        }
    }
    // ---- col-tiles 1-3 -> 96 VGPRs (asm volatile: cannot rematerialize) ----
    bf16x8 wf1[8], wf2[8], wf3[8];
    {
        const u16* bp1 = Wrb + (size_t)(ns * 64 + 16 + lcol) * R_ + w * 256 + lkh * 8;
        const u16* bp2 = Wrb + (size_t)(ns * 64 + 32 + lcol) * R_ + w * 256 + lkh * 8;
        const u16* bp3 = Wrb + (size_t)(ns * 64 + 48 + lcol) * R_ + w * 256 + lkh * 8;
        #define WL(dst, bp, OFF) \
            asm volatile("global_load_dwordx4 %0, %1, off offset:" OFF \
                         : "=v"(dst) : "v"(bp))
        WL(wf1[0], bp1, "0");   WL(wf1[1], bp1, "64");  WL(wf1[2], bp1, "128");
        WL(wf1[3], bp1, "192"); WL(wf1[4], bp1, "256"); WL(wf1[5], bp1, "320");
        WL(wf1[6], bp1, "384"); WL(wf1[7], bp1, "448");
        WL(wf2[0], bp2, "0");   WL(wf2[1], bp2, "64");  WL(wf2[2], bp2, "128");
        WL(wf2[3], bp2, "192"); WL(wf2[4], bp2, "256"); WL(wf2[5], bp2, "320");
        WL(wf2[6], bp2, "384"); WL(wf2[7], bp2, "448");
        WL(wf3[0], bp3, "0");   WL(wf3[1], bp3, "64");  WL(wf3[2], bp3, "128");
        WL(wf3[3], bp3, "192"); WL(wf3[4], bp3, "256"); WL(wf3[5], bp3, "320");
        WL(wf3[6], bp3, "384"); WL(wf3[7], bp3, "448");
        #undef WL
    }
    // input-projection W fragments (waves 0-3, tile w)
    bf16x8 wi[4];
    float bs = 0.f;
    if (w < 4) {
        const u16* wp = Wib + (size_t)(ns * 64 + w * 16 + lcol) * I_ + lkh * 8;
        asm volatile("global_load_dwordx4 %0, %1, off"            : "=v"(wi[0]) : "v"(wp));
        asm volatile("global_load_dwordx4 %0, %1, off offset:64"  : "=v"(wi[1]) : "v"(wp));
        asm volatile("global_load_dwordx4 %0, %1, off offset:128" : "=v"(wi[2]) : "v"(wp));
        asm volatile("global_load_dwordx4 %0, %1, off offset:192" : "=v"(wi[3]) : "v"(wp));
        bs = bias[ns * 64 + w * 16 + lcol];
    }
    asm volatile("s_waitcnt vmcnt(0)" ::: "memory");
    __builtin_amdgcn_sched_barrier(0);

    char* ringB = (char*)ring + (size_t)grp * RSTRIDE;
    const char* zb = (const char*)zpage;
    const float* xrow = input + (size_t)(grp * 8 + (arow & 7)) * T_ * I_;
    const char* wl0 = wlds + ((size_t)w * 8 * 64 + lane) * 16;   // my tile-0 base

    #define LOAD8(F)                                                          \
        asm volatile(                                                         \
            "global_load_dwordx4 %0, %8, off " F "\n\t"                       \
            "global_load_dwordx4 %1, %8, off offset:64 " F "\n\t"             \
            "global_load_dwordx4 %2, %8, off offset:128 " F "\n\t"            \
            "global_load_dwordx4 %3, %8, off offset:192 " F "\n\t"            \
            "global_load_dwordx4 %4, %8, off offset:256 " F "\n\t"            \
            "global_load_dwordx4 %5, %8, off offset:320 " F "\n\t"            \
            "global_load_dwordx4 %6, %8, off offset:384 " F "\n\t"            \
            "global_load_dwordx4 %7, %8, off offset:448 " F "\n\t"            \
            "s_waitcnt vmcnt(0)"                                              \
            : "=&v"(h0), "=&v"(h1), "=&v"(h2), "=&v"(h3),                     \
              "=&v"(h4), "=&v"(h5), "=&v"(h6), "=&v"(h7)                      \
            : "v"(Ah)                                                         \
            : "memory")

    int rs = 0;
    for (int t = 0; t < T_; ++t) {
        const int wsl = (rs + 1 == NSLOT) ? 0 : rs + 1;
        const int ps  = (rs == 0) ? NSLOT - 1 : rs - 1;
        const char* slotR = ringB + (size_t)rs  * SLOTB;
        char*       slotW = ringB + (size_t)wsl * SLOTB;
        char*       slotP = ringB + (size_t)ps  * SLOTB;

        // ---- input projection (waves 0-3, tile w; independent of h) ----
        f32x4 facc = {0.f, 0.f, 0.f, 0.f};
        if (w < 4) {
            const float* Ax = xrow + (size_t)t * I_ + lkh * 8;
            const f32x4 z4 = {0.f, 0.f, 0.f, 0.f};
            #pragma unroll
            for (int kc = 0; kc < 4; ++kc) {
                f32x4 xa = z4, xb = z4;
                if (arow < 8) {
                    xa = *reinterpret_cast<const f32x4*>(Ax + kc * 32);
                    xb = *reinterpret_cast<const f32x4*>(Ax + kc * 32 + 4);
                }
                facc = __builtin_amdgcn_mfma_f32_16x16x32_bf16(cvt8r(xa, xb), wi[kc], facc, 0, 0, 0);
            }
        }

        // ---- poll+load h A-fragments (NaN sentinel; rows 8-15 = zero page) ----
        const char* base = (arow < 8) ? (slotR + arow * 4096) : zb;
        const char* Ah = base + (size_t)(w * 256 + lkh * 8) * 2;
        bf16x8 h0, h1, h2, h3, h4, h5, h6, h7;
        {
            u32 bad; int anybad; int spins = 0;
            do {
                if (ic) { LOAD8("sc1"); } else { LOAD8("sc0"); }
                __builtin_amdgcn_sched_barrier(0);
                bad = sentchk(h0) | sentchk(h1) | sentchk(h2) | sentchk(h3) |
                      sentchk(h4) | sentchk(h5) | sentchk(h6) | sentchk(h7);
                anybad = __any((int)bad);
                if (anybad && !ic && ++spins >= 64) ic = true;   // sticky escape
            } while (anybad);
        }

        // ---- recurrent MFMAs: K-eighth w; tile0 B-frags from LDS, 1-3 regs ----
        f32x4 acc0 = {0.f,0.f,0.f,0.f}, acc1 = {0.f,0.f,0.f,0.f};
        f32x4 acc2 = {0.f,0.f,0.f,0.f}, acc3 = {0.f,0.f,0.f,0.f};
        #define RSTEP(J, HJ)                                                      \
        {                                                                         \
            bf16x8 b0 = *reinterpret_cast<const bf16x8*>(wl0 + (J) * 1024);       \
            acc0 = __builtin_amdgcn_mfma_f32_16x16x32_bf16(HJ, b0,      acc0, 0, 0, 0); \
            acc1 = __builtin_amdgcn_mfma_f32_16x16x32_bf16(HJ, wf1[J],  acc1, 0, 0, 0); \
            acc2 = __builtin_amdgcn_mfma_f32_16x16x32_bf16(HJ, wf2[J],  acc2, 0, 0, 0); \
            acc3 = __builtin_amdgcn_mfma_f32_16x16x32_bf16(HJ, wf3[J],  acc3, 0, 0, 0); \
        }
        RSTEP(0, h0) RSTEP(1, h1) RSTEP(2, h2) RSTEP(3, h3)
        RSTEP(4, h4) RSTEP(5, h5) RSTEP(6, h6) RSTEP(7, h7)
        #undef RSTEP

        red[w][0][lane] = acc0;
        red[w][1][lane] = acc1;
        red[w][2][lane] = acc2;
        red[w][3][lane] = acc3;
        __syncthreads();                 // b1: all partials visible

        // ---- tail: wave w<4 reduces tile w, adds xin+bias, tanh ----
        if (w < 4) {
            f32x4 tot = red[0][w][lane];
            #pragma unroll
            for (int ww = 1; ww < 8; ++ww) tot += red[ww][w][lane];
            tot += facc;
            #pragma unroll
            for (int i = 0; i < 4; ++i) {
                int orow = lkh * 4 + i;  // C layout: col=lane&15, row=lkh*4+i
                if (orow < 8)
                    xout[orow][w * 16 + lcol] = f2bf(tanhf(tot[i] + bs));
            }
        }
        __syncthreads();                 // b2: xout complete

        if (w == 0) {                    // publish: sc1 write-through
            bf16x8 v = ldbf8(&xout[lane >> 3][(lane & 7) * 8]);
            char* dst = slotW + (size_t)(lane >> 3) * 4096 + ns * 128 + (lane & 7) * 16;
            asm volatile("global_store_dwordx4 %0, %1, off sc1"
                         :: "v"(dst), "v"(v) : "memory");
        }
        if (w == 1) {                    // re-poison slot consumed at t-1
            u32x4 sq = {0x7FC07FC0u, 0x7FC07FC0u, 0x7FC07FC0u, 0x7FC07FC0u};
            char* dst = slotP + (size_t)(lane >> 3) * 4096 + ns * 128 + (lane & 7) * 16;
            asm volatile("global_store_dwordx4 %0, %1, off sc1"
                         :: "v"(dst), "v"(sq) : "memory");
        }
        if (w == 2 && t == T_ - 1) {     // final h -> hfinal (plain stores)
            bf16x8 v = ldbf8(&xout[lane >> 3][(lane & 7) * 8]);
            *reinterpret_cast<bf16x8*>(
                hfinal + (size_t)(grp * 8 + (lane >> 3)) * R_ + ns * 64 + (lane & 7) * 8) = v;
        }
        rs = wsl;
    }
    #undef LOAD8
}

// ---- readout ------------------------------------------------------------
__global__ __launch_bounds__(128) void readout_kernel(
    const u16* __restrict__ h, const u16* __restrict__ Wo,
    const float* __restrict__ b_out, float* __restrict__ out)
{
    const int lane = threadIdx.x & 63;
    const int wid  = threadIdx.x >> 6;
    const int g    = blockIdx.x * 2 + wid;   // 0..63
    const int m    = g >> 4;
    const int n    = g & 15;
    const int koff = (lane >> 4) * 8;
    const int b    = m * 16 + (lane & 15);
    const int col  = n * 16 + (lane & 15);

    f32x4 acc0 = {0.f,0.f,0.f,0.f};
    f32x4 acc1 = {0.f,0.f,0.f,0.f};
    f32x4 acc2 = {0.f,0.f,0.f,0.f};
    f32x4 acc3 = {0.f,0.f,0.f,0.f};

    const u16* Ah = h + (size_t)b * R_ + koff;
    const u16* Bh = Wo + (size_t)col * R_ + koff;
    #pragma unroll 4
    for (int kc = 0; kc < 64; kc += 4) {
        acc0 = __builtin_amdgcn_mfma_f32_16x16x32_bf16(ldbf8(Ah + (kc + 0) * 32), ldbf8(Bh + (kc + 0) * 32), acc0, 0, 0, 0);
        acc1 = __builtin_amdgcn_mfma_f32_16x16x32_bf16(ldbf8(Ah + (kc + 1) * 32), ldbf8(Bh + (kc + 1) * 32), acc1, 0, 0, 0);
        acc2 = __builtin_amdgcn_mfma_f32_16x16x32_bf16(ldbf8(Ah + (kc + 2) * 32), ldbf8(Bh + (kc + 2) * 32), acc2, 0, 0, 0);
        acc3 = __builtin_amdgcn_mfma_f32_16x16x32_bf16(ldbf8(Ah + (kc + 3) * 32), ldbf8(Bh + (kc + 3) * 32), acc3, 0, 0, 0);
    }

    f32x4 s = acc0 + acc1 + acc2 + acc3;
    const float bo = b_out[col];
    #pragma unroll
    for (int i2 = 0; i2 < 4; ++i2) {
        int row = m * 16 + (lane >> 4) * 4 + i2;
        out[(size_t)row * O_ + col] = s[i2] + bo;
    }
}

// ---- launch -------------------------------------------------------------

extern "C" void kernel_launch(void* const* d_in, const int* in_sizes, int n_in,
                              void* d_out, int out_size, void* d_ws, size_t ws_size,
                              hipStream_t stream) {
    const float* in    = (const float*)d_in[0];
    const float* Winw  = (const float*)d_in[1];
    const float* Winb  = (const float*)d_in[2];
    const float* Wresw = (const float*)d_in[3];
    const float* Wresb = (const float*)d_in[4];
    const float* Woutw = (const float*)d_in[5];
    const float* Woutb = (const float*)d_in[6];
    float* out = (float*)d_out;

    char* ws = (char*)d_ws;
    u16*   Wrb    = (u16*)(ws);                    // 2048*2048*2 = 8388608
    u16*   Wib    = (u16*)(ws + 8388608);          // 2048*128*2  = 524288
    u16*   Wob    = (u16*)(ws + 8912896);          // 256*2048*2  = 1048576
    float* bias   = (float*)(ws + 9961472);        // 2048*4      = 8192
    u16*   hfinal = (u16*)(ws + 9969664);          // 64*2048*2   = 262144
    u16*   zpage  = (u16*)(ws + 10231808);         // 4096
    u32*   cnt    = (u32*)(ws + 10235904);         // 64
    u16*   ring   = (u16*)(ws + 10235968);         // 8*65*32768  = 17039360
    // total: 27275328 bytes (~26 MB)

    conv_bf16_kernel<<<2048, 256, 0, stream>>>(Wresw, Wrb, R_ * R_);
    conv_bf16_kernel<<<256, 256, 0, stream>>>(Winw, Wib, R_ * I_);
    conv_bf16_kernel<<<512, 256, 0, stream>>>(Woutw, Wob, O_ * R_);
    bias_sum_kernel<<<8, 256, 0, stream>>>(Winb, Wresb, bias, R_);
    ring_init_kernel<<<4096, 256, 0, stream>>>((u32*)ring);
    hipMemsetAsync(zpage, 0, 4096 + 64, stream);   // zero page + counters

    esn_persist<<<NBLK, 512, 0, stream>>>(Wrb, Wib, in, bias,
                                          ring, zpage, cnt, hfinal);

    readout_kernel<<<32, 128, 0, stream>>>(hfinal, Wob, Woutb, out);
}